// Round 6
// baseline (375.290 us; speedup 1.0000x reference)
//
#include <hip/hip_runtime.h>
#include <math.h>

// Problem constants (from reference)
constexpr int B_SZ = 16384;
constexpr long long CELLS = 4194304;   // 16384*256 cells, 2 anchor slots each
constexpr int CLS_CELLS = 8192;        // logits[:batch_size] -> first 8192 cells get cls loss
constexpr float NOOBJ_SCALE = 0.5f;
constexpr float COORD_SCALE = 5.0f;
constexpr int NSLOTS = 64;             // atomic scatter slots in d_ws

typedef float vf4 __attribute__((ext_vector_type(4)));

// Per-(cell,slot) loss contribution.
// pred slot layout: offset=p0, dur=p1, conf=p2, cls=p3..p5  (slot1: +6)
// target slot layout: conf, cls, offset, dur                (slot1: +4)
__device__ __forceinline__ float slot_loss(float pc, float l0, float l1, float l2,
                                           float po, float pd,
                                           float tc, float tcls, float to, float td,
                                           bool do_cls) {
    float d = tc - pc;
    bool obj = (tc == 1.0f);
    float w = obj ? 1.0f : ((tc == 0.0f) ? NOOBJ_SCALE : 0.0f);
    float r = w * d * d;

    if (obj) {
        float doff = to - po;
        r += COORD_SCALE * doff * doff;
        float dd = sqrtf(td) - sqrtf(pd);
        r += COORD_SCALE * dd * dd;
    }
    if (do_cls) {
        float x0, x1, x2;
        int idx;
        if (obj) { x0 = l0; x1 = l1; x2 = l2; idx = (int)tcls; }
        else     { x0 = 0.f; x1 = 0.f; x2 = 0.f; idx = 0; }
        float m = fmaxf(x0, fmaxf(x1, x2));
        float lse = logf(expf(x0 - m) + expf(x1 - m) + expf(x2 - m)) + m;
        float li = (idx == 0) ? x0 : ((idx == 1) ? x1 : x2);
        r += lse - li;   // cross-entropy = logsumexp - logit[target]
    }
    return r;
}

// 2 adjacent cells per thread, straight-line, ALL loads nontemporal (nt flag:
// evict-first / no-allocate) — tests whether L2/L3 line allocation on a pure
// 335 MB streaming read is what throttles the miss/fill pipeline.
__global__ __launch_bounds__(256) void ensemble_loss_kernel(
        const float* __restrict__ pred,
        const float* __restrict__ target,
        double* __restrict__ acc_ws) {
    const long long t = (long long)blockIdx.x * blockDim.x + threadIdx.x;  // 0..2M-1
    const vf4* __restrict__ p4 = (const vf4*)pred + t * 6;   // 2 cells x 3 float4
    const vf4* __restrict__ t4 = (const vf4*)target + t * 4; // 2 cells x 2 float4

    // 10 independent nontemporal 16B loads, issued as one batch.
    vf4 a0 = __builtin_nontemporal_load(p4 + 0);
    vf4 a1 = __builtin_nontemporal_load(p4 + 1);
    vf4 a2 = __builtin_nontemporal_load(p4 + 2);
    vf4 a3 = __builtin_nontemporal_load(p4 + 3);
    vf4 a4 = __builtin_nontemporal_load(p4 + 4);
    vf4 a5 = __builtin_nontemporal_load(p4 + 5);
    vf4 b0 = __builtin_nontemporal_load(t4 + 0);
    vf4 b1 = __builtin_nontemporal_load(t4 + 1);
    vf4 b2 = __builtin_nontemporal_load(t4 + 2);
    vf4 b3 = __builtin_nontemporal_load(t4 + 3);

    // cells 2t and 2t+1 both < 8192  <=>  t < 4096
    const bool do_cls = (t < (CLS_CELLS >> 1));

    float acc = 0.0f;
    // cell 2t:   pred = a0..a2, target = b0 (slot0), b1 (slot1)
    acc += slot_loss(a0.z, a0.w, a1.x, a1.y, a0.x, a0.y,
                     b0.x, b0.y, b0.z, b0.w, do_cls);
    acc += slot_loss(a2.x, a2.y, a2.z, a2.w, a1.z, a1.w,
                     b1.x, b1.y, b1.z, b1.w, do_cls);
    // cell 2t+1: pred = a3..a5, target = b2 (slot0), b3 (slot1)
    acc += slot_loss(a3.z, a3.w, a4.x, a4.y, a3.x, a3.y,
                     b2.x, b2.y, b2.z, b2.w, do_cls);
    acc += slot_loss(a5.x, a5.y, a5.z, a5.w, a4.z, a4.w,
                     b3.x, b3.y, b3.z, b3.w, do_cls);

    // wave(64) shuffle reduction
    for (int off = 32; off > 0; off >>= 1)
        acc += __shfl_down(acc, off, 64);

    __shared__ float wsum[4];  // 256 threads = 4 waves
    int lane = threadIdx.x & 63;
    int wv = threadIdx.x >> 6;
    if (lane == 0) wsum[wv] = acc;
    __syncthreads();
    if (threadIdx.x == 0) {
        float s = wsum[0] + wsum[1] + wsum[2] + wsum[3];
        atomicAdd(&acc_ws[blockIdx.x & (NSLOTS - 1)], (double)s);
    }
}

__global__ void finalize_kernel(const double* __restrict__ acc_ws,
                                float* __restrict__ out) {
    double s = 0.0;
    #pragma unroll
    for (int i = 0; i < NSLOTS; ++i) s += acc_ws[i];
    out[0] = (float)(s * (1.0 / (double)B_SZ));
}

extern "C" void kernel_launch(void* const* d_in, const int* in_sizes, int n_in,
                              void* d_out, int out_size, void* d_ws, size_t ws_size,
                              hipStream_t stream) {
    const float* pred   = (const float*)d_in[0];
    const float* target = (const float*)d_in[1];
    float* out = (float*)d_out;
    double* acc = (double*)d_ws;

    // d_ws is poisoned 0xAA before every launch — zero the accumulator slots.
    hipMemsetAsync(d_ws, 0, NSLOTS * sizeof(double), stream);

    // Exact cover: 8192 blocks x 256 threads x 2 cells = 4,194,304 cells.
    ensemble_loss_kernel<<<8192, 256, 0, stream>>>(pred, target, acc);
    finalize_kernel<<<1, 1, 0, stream>>>(acc, out);
}